// Round 3
// baseline (376.921 us; speedup 1.0000x reference)
//
#include <hip/hip_runtime.h>
#include <hip/hip_fp16.h>
#include <hip/hip_cooperative_groups.h>

namespace cg = cooperative_groups;

// Problem constants: B=2, CIN=32, COUT=64, K=9, H=256, W=512, OH=256, OW=512
#define HW_IN   131072
#define W_IN    512
#define H_IN    256
#define HW_OUT  131072
#define CIN     32
#define COUT    64
#define KK      9
#define BB      2

typedef _Float16 hf2 __attribute__((ext_vector_type(2)));
typedef _Float16 hf4 __attribute__((ext_vector_type(4)));
typedef _Float16 hf8 __attribute__((ext_vector_type(8)));
typedef float f32x2 __attribute__((ext_vector_type(2)));
typedef float f32x4 __attribute__((ext_vector_type(4)));

static __device__ __forceinline__ hf8 u4h(uint4 u) {
  return __builtin_bit_cast(hf8, u);
}

// ---------------------------------------------------------------------------
// R7: single cooperative kernel. Rationale: three structurally different
// transpose kernels (R0/R1/R2) all left the same ~90us residual vs the conv
// dispatch time, while roofline arithmetic bounds the transpose at <=20us
// (48MB coalesced, 8 waves/CU x 16KB in flight, ~2us LDS cost). Conclusion:
// the residual lives BETWEEN the two dispatches (launch/serialization
// overhead in the timed window), not inside the transpose. Fusing into one
// dispatch both removes that overhead and makes the true phase cost visible
// as a single top-5 rocprof row (no more subtraction).
//
// Geometry: 1024 blocks = exactly 4/CU (LDS 36KB -> 4.44/CU, launch_bounds
// caps VGPR at 128; conv needs 64). Phase A transposes a 128-pixel window
// (wave-instr = one full 512B plane-row read; 1KB-contiguous xt stores).
// this_grid().sync() (device-scope fence). Phase B stages weights into the
// SAME LDS buffer (union with transpose scratch) and runs 4 conv tiles
// grid-strided, inner loop byte-identical to R2.
// ---------------------------------------------------------------------------
__global__ __launch_bounds__(256, 4) void fused_mapped_conv(
    const float* __restrict__ x,        // [BB][CIN][H*W] fp32
    const float* __restrict__ weight,   // [COUT][CIN][KK] fp32
    const float* __restrict__ bias,     // [COUT]
    const float* __restrict__ sm,       // [HW_OUT][KK][2] fp32
    _Float16* xt,                       // ws: [H*W][BB*CIN] f16
    float* __restrict__ out) {          // [BB][COUT][HW_OUT] fp32
  __shared__ __align__(16) _Float16 smem[KK * COUT * CIN];  // 36 KB

  int t = threadIdx.x;
  int wave = t >> 6, lane = t & 63;

  // ---- Phase A: transpose this block's 128-pixel window into xt ----
  {
    _Float16 (*lt)[132] = (_Float16 (*)[132])smem;   // 64 x 132 f16 = 16.9 KB
    int hwbase = blockIdx.x * 128;
    // 64 plane-rows of 128 floats; wave w takes planes {i*4+w}; one
    // wave-instruction = one full 512B contiguous plane-row.
#pragma unroll
    for (int i = 0; i < 16; ++i) {
      int p = i * 4 + wave;
      f32x2 v = *((const f32x2*)(x + (size_t)p * HW_IN + hwbase) + lane);
      hf2 h; h[0] = (_Float16)v[0]; h[1] = (_Float16)v[1];
      *(hf2*)&lt[p][lane * 2] = h;
    }
    __syncthreads();
    // Scatter out: thread -> granule gg (8 channels) of pixel hwl; a wave's
    // 64 stores tile 8 consecutive pixels' 128B records = 1KB contiguous.
    int gg  = t & 7;
    int hl0 = t >> 3;
#pragma unroll
    for (int j = 0; j < 4; ++j) {
      int hwl = hl0 + j * 32;
      hf8 h;
#pragma unroll
      for (int c = 0; c < 8; ++c) h[c] = lt[gg * 8 + c][hwl];
      *(hf8*)(xt + (size_t)(hwbase + hwl) * 64 + gg * 8) = h;
    }
  }

  cg::this_grid().sync();   // all xt writes visible device-wide

  // ---- Phase B: stage weights, then 4 grid-strided conv tiles ----
  for (int j = t; j < COUT * CIN * KK; j += 256) {
    unsigned ju = (unsigned)j;
    unsigned o  = ju / 288u;
    unsigned rr = ju % 288u;
    unsigned c  = rr / 9u;
    unsigned k  = rr % 9u;
    smem[(k * 64u + o) * 32u + c] = (_Float16)weight[ju];
  }
  __syncthreads();

  int m    = lane & 15;   // A-row: pixel; B-col: cout within N-tile
  int quad = lane >> 4;   // channel quarter (A) / k-chunk (B) / row group (C)
  const uint4* xt4 = (const uint4*)xt;
  const uint4* wbl = (const uint4*)smem + (size_t)(m * 4 + quad);

#pragma unroll 1
  for (int it = 0; it < 4; ++it) {
    int tile = blockIdx.x + it * 1024;              // 4096 tiles of 64 pixels
    int pix_base = tile * 64 + wave * 16;
    int pix  = pix_base + m;
    int b    = pix_base >> 17;                      // wave-uniform
    int hw   = pix & (HW_OUT - 1);
    int hw_base = pix_base & (HW_OUT - 1);
    int bq = b * 4 + quad;   // uint4-granule within a pixel's 64 halves

    f32x4 acc[4] = {{0.f,0.f,0.f,0.f},{0.f,0.f,0.f,0.f},
                    {0.f,0.f,0.f,0.f},{0.f,0.f,0.f,0.f}};
    const float* smp = sm + (size_t)hw * (KK * 2);

#pragma unroll 3
    for (int k = 0; k < KK; ++k) {
      float sx = smp[k * 2 + 0];
      float sy = smp[k * 2 + 1];
      float bxf = floorf(sx), byf = floorf(sy);
      float fx = sx - bxf, fy = sy - byf;
      int ix0 = (int)bxf, iy0 = (int)byf;
      int ix1 = min(ix0 + 1, W_IN - 1);
      int iy1 = min(iy0 + 1, H_IN - 1);
      ix0 = max(min(ix0, W_IN - 1), 0); ix1 = max(ix1, 0);
      iy0 = max(min(iy0, H_IN - 1), 0); iy1 = max(iy1, 0);

      uint4 v00 = xt4[(iy0 * W_IN + ix0) * 8 + bq];
      uint4 v01 = xt4[(iy0 * W_IN + ix1) * 8 + bq];
      uint4 v10 = xt4[(iy1 * W_IN + ix0) * 8 + bq];
      uint4 v11 = xt4[(iy1 * W_IN + ix1) * 8 + bq];

      _Float16 w00 = (_Float16)((1.f - fx) * (1.f - fy));
      _Float16 w01 = (_Float16)(fx * (1.f - fy));
      _Float16 w10 = (_Float16)((1.f - fx) * fy);
      _Float16 w11 = (_Float16)(fx * fy);
      hf8 h00 = {w00, w00, w00, w00, w00, w00, w00, w00};
      hf8 h01 = {w01, w01, w01, w01, w01, w01, w01, w01};
      hf8 h10 = {w10, w10, w10, w10, w10, w10, w10, w10};
      hf8 h11 = {w11, w11, w11, w11, w11, w11, w11, w11};

      hf8 a = h00 * u4h(v00) + h01 * u4h(v01) + h10 * u4h(v10) + h11 * u4h(v11);

      const uint4* wk = wbl + (size_t)k * 256;   // per-k block = 64 o x 4 granules
      hf8 b0 = u4h(wk[0]);
      hf8 b1 = u4h(wk[64]);
      hf8 b2 = u4h(wk[128]);
      hf8 b3 = u4h(wk[192]);

      acc[0] = __builtin_amdgcn_mfma_f32_16x16x32_f16(a, b0, acc[0], 0, 0, 0);
      acc[1] = __builtin_amdgcn_mfma_f32_16x16x32_f16(a, b1, acc[1], 0, 0, 0);
      acc[2] = __builtin_amdgcn_mfma_f32_16x16x32_f16(a, b2, acc[2], 0, 0, 0);
      acc[3] = __builtin_amdgcn_mfma_f32_16x16x32_f16(a, b3, acc[3], 0, 0, 0);
    }

    // Epilogue: lane writes 4 consecutive pixels (rows quad*4..+3) for cout n.
    int hw0 = hw_base + quad * 4;
#pragma unroll
    for (int nt = 0; nt < 4; ++nt) {
      int n = nt * 16 + m;
      float bn = bias[n];
      float4 v = make_float4(acc[nt][0] + bn, acc[nt][1] + bn,
                             acc[nt][2] + bn, acc[nt][3] + bn);
      float* op = out + (size_t)(b * COUT + n) * HW_OUT + hw0;
      *(float4*)op = v;
    }
  }
}

// ---------------------------------------------------------------------------
// Fallback pair (R2-identical) in case cooperative launch is rejected.
// ---------------------------------------------------------------------------
__global__ __launch_bounds__(256) void transpose_lds(
    const float* __restrict__ x, _Float16* __restrict__ xt) {
  __shared__ _Float16 lt[64][260];
  int t = threadIdx.x;
  int wave = t >> 6, lane = t & 63;
  int hwbase = blockIdx.x * 256;
#pragma unroll
  for (int i = 0; i < 16; ++i) {
    int p = i * 4 + wave;
    f32x4 v = *((const f32x4*)(x + (size_t)p * HW_IN + hwbase) + lane);
    hf4 h;
    h[0] = (_Float16)v[0]; h[1] = (_Float16)v[1];
    h[2] = (_Float16)v[2]; h[3] = (_Float16)v[3];
    *(hf4*)&lt[p][lane * 4] = h;
  }
  __syncthreads();
  int gg  = t & 7;
  int hl0 = t >> 3;
#pragma unroll
  for (int j = 0; j < 8; ++j) {
    int hwl = hl0 + j * 32;
    hf8 h;
#pragma unroll
    for (int c = 0; c < 8; ++c) h[c] = lt[gg * 8 + c][hwl];
    *(hf8*)(xt + (size_t)(hwbase + hwl) * 64 + gg * 8) = h;
  }
}

__global__ __launch_bounds__(256, 4) void mapped_conv_mfma(
    const _Float16* __restrict__ xt,
    const float* __restrict__ weight,
    const float* __restrict__ bias,
    const float* __restrict__ sm,
    float* __restrict__ out) {
  __shared__ __align__(16) _Float16 w_lds[KK * COUT * CIN];
  int t = threadIdx.x;
  for (int j = t; j < COUT * CIN * KK; j += 256) {
    unsigned ju = (unsigned)j;
    unsigned o  = ju / 288u;
    unsigned rr = ju % 288u;
    unsigned c  = rr / 9u;
    unsigned k  = rr % 9u;
    w_lds[(k * 64u + o) * 32u + c] = (_Float16)weight[ju];
  }
  __syncthreads();

  int wave = t >> 6;
  int lane = t & 63;
  int m    = lane & 15;
  int quad = lane >> 4;
  int pix_base = blockIdx.x * 64 + wave * 16;
  int pix  = pix_base + m;
  int b    = pix_base >> 17;
  int hw   = pix & (HW_OUT - 1);
  int hw_base = pix_base & (HW_OUT - 1);
  const uint4* xt4 = (const uint4*)xt;
  int bq = b * 4 + quad;

  f32x4 acc[4] = {{0.f,0.f,0.f,0.f},{0.f,0.f,0.f,0.f},
                  {0.f,0.f,0.f,0.f},{0.f,0.f,0.f,0.f}};
  const float* smp = sm + (size_t)hw * (KK * 2);
  const uint4* wbl = (const uint4*)w_lds + (size_t)(m * 4 + quad);

#pragma unroll 3
  for (int k = 0; k < KK; ++k) {
    float sx = smp[k * 2 + 0];
    float sy = smp[k * 2 + 1];
    float bxf = floorf(sx), byf = floorf(sy);
    float fx = sx - bxf, fy = sy - byf;
    int ix0 = (int)bxf, iy0 = (int)byf;
    int ix1 = min(ix0 + 1, W_IN - 1);
    int iy1 = min(iy0 + 1, H_IN - 1);
    ix0 = max(min(ix0, W_IN - 1), 0); ix1 = max(ix1, 0);
    iy0 = max(min(iy0, H_IN - 1), 0); iy1 = max(iy1, 0);

    uint4 v00 = xt4[(iy0 * W_IN + ix0) * 8 + bq];
    uint4 v01 = xt4[(iy0 * W_IN + ix1) * 8 + bq];
    uint4 v10 = xt4[(iy1 * W_IN + ix0) * 8 + bq];
    uint4 v11 = xt4[(iy1 * W_IN + ix1) * 8 + bq];

    _Float16 w00 = (_Float16)((1.f - fx) * (1.f - fy));
    _Float16 w01 = (_Float16)(fx * (1.f - fy));
    _Float16 w10 = (_Float16)((1.f - fx) * fy);
    _Float16 w11 = (_Float16)(fx * fy);
    hf8 h00 = {w00, w00, w00, w00, w00, w00, w00, w00};
    hf8 h01 = {w01, w01, w01, w01, w01, w01, w01, w01};
    hf8 h10 = {w10, w10, w10, w10, w10, w10, w10, w10};
    hf8 h11 = {w11, w11, w11, w11, w11, w11, w11, w11};

    hf8 a = h00 * u4h(v00) + h01 * u4h(v01) + h10 * u4h(v10) + h11 * u4h(v11);

    const uint4* wk = wbl + (size_t)k * 256;
    hf8 b0 = u4h(wk[0]);
    hf8 b1 = u4h(wk[64]);
    hf8 b2 = u4h(wk[128]);
    hf8 b3 = u4h(wk[192]);

    acc[0] = __builtin_amdgcn_mfma_f32_16x16x32_f16(a, b0, acc[0], 0, 0, 0);
    acc[1] = __builtin_amdgcn_mfma_f32_16x16x32_f16(a, b1, acc[1], 0, 0, 0);
    acc[2] = __builtin_amdgcn_mfma_f32_16x16x32_f16(a, b2, acc[2], 0, 0, 0);
    acc[3] = __builtin_amdgcn_mfma_f32_16x16x32_f16(a, b3, acc[3], 0, 0, 0);
  }

  int hw0 = hw_base + quad * 4;
#pragma unroll
  for (int nt = 0; nt < 4; ++nt) {
    int n = nt * 16 + m;
    float bn = bias[n];
    float4 v = make_float4(acc[nt][0] + bn, acc[nt][1] + bn,
                           acc[nt][2] + bn, acc[nt][3] + bn);
    float* op = out + (size_t)(b * COUT + n) * HW_OUT + hw0;
    *(float4*)op = v;
  }
}

extern "C" void kernel_launch(void* const* d_in, const int* in_sizes, int n_in,
                              void* d_out, int out_size, void* d_ws, size_t ws_size,
                              hipStream_t stream) {
  const float* x  = (const float*)d_in[0];   // [B][CIN][H*W]
  const float* w  = (const float*)d_in[1];   // [COUT][CIN][KK]
  const float* bs = (const float*)d_in[2];   // [COUT]
  const float* sm = (const float*)d_in[3];   // [OH*OW][KK][2]
  float* out = (float*)d_out;                // [B][COUT][OH*OW]
  _Float16* xt = (_Float16*)d_ws;            // 16 MB scratch: (H*W, B, CIN) f16

  void* args[] = {(void*)&x, (void*)&w, (void*)&bs, (void*)&sm,
                  (void*)&xt, (void*)&out};
  hipError_t e = hipLaunchCooperativeKernel(
      reinterpret_cast<const void*>(&fused_mapped_conv),
      dim3(1024), dim3(256), args, 0, stream);
  if (e != hipSuccess) {
    // Fallback: R2 two-kernel path.
    transpose_lds<<<dim3(512), dim3(256), 0, stream>>>(x, xt);
    mapped_conv_mfma<<<dim3(4096), dim3(256), 0, stream>>>(xt, w, bs, sm, out);
  }
}

// Round 4
// 190.323 us; speedup vs baseline: 1.9804x; 1.9804x over previous
//
#include <hip/hip_runtime.h>
#include <hip/hip_fp16.h>

// Problem constants: B=2, CIN=32, COUT=64, K=9, H=256, W=512, OH=256, OW=512
#define HW_IN   131072
#define W_IN    512
#define H_IN    256
#define HW_OUT  131072
#define CIN     32
#define COUT    64
#define KK      9
#define BB      2

typedef _Float16 hf2 __attribute__((ext_vector_type(2)));
typedef _Float16 hf4 __attribute__((ext_vector_type(4)));
typedef _Float16 hf8 __attribute__((ext_vector_type(8)));
typedef float f32x4 __attribute__((ext_vector_type(4)));

static __device__ __forceinline__ hf8 u4h(uint4 u) {
  return __builtin_bit_cast(hf8, u);
}

// ---------------------------------------------------------------------------
// Kernel 1: transpose x (B,CIN,H*W) fp32 -> xt (H*W, B, CIN) f16, via LDS.
// R3 established this costs only ~5us (the ~90us "residual" every round is
// FIXED harness overhead: single-dispatch R3 still showed dur_us - kernel
// = 95us). Keep the R2 version: 1KB-contiguous plane-row reads, LDS turn,
// 1KB-contiguous record stores.
// ---------------------------------------------------------------------------
__global__ __launch_bounds__(256) void transpose_lds(
    const float* __restrict__ x, _Float16* __restrict__ xt) {
  __shared__ _Float16 lt[64][260];   // 33.3 KB, row stride 520B
  int t = threadIdx.x;
  int wave = t >> 6, lane = t & 63;
  int hwbase = blockIdx.x * 256;

#pragma unroll
  for (int i = 0; i < 16; ++i) {
    int p = i * 4 + wave;
    f32x4 v = *((const f32x4*)(x + (size_t)p * HW_IN + hwbase) + lane);
    hf4 h;
    h[0] = (_Float16)v[0]; h[1] = (_Float16)v[1];
    h[2] = (_Float16)v[2]; h[3] = (_Float16)v[3];
    *(hf4*)&lt[p][lane * 4] = h;
  }
  __syncthreads();

  int gg  = t & 7;
  int hl0 = t >> 3;
#pragma unroll
  for (int j = 0; j < 8; ++j) {
    int hwl = hl0 + j * 32;
    hf8 h;
#pragma unroll
    for (int c = 0; c < 8; ++c) h[c] = lt[gg * 8 + c][hwl];
    *(hf8*)(xt + (size_t)(hwbase + hwl) * 64 + gg * 8) = h;
  }
}

// ---------------------------------------------------------------------------
// Kernel 2: fused gather + MFMA contraction, R4 batch-paired.
// sample_map is batch-independent, so b0 and b1 read the SAME 4 corner
// records per tap. Previously b0/b1 lived in blocks 2048 apart (never
// co-resident) -> the adjacent 64B half of each 128B record was refetched.
// Now one wave processes 16 pixels x BOTH batches: per tap-corner the wave
// touches the full 128B record, and the (ix0,ix1) corner pair makes the
// access 2 x 256B fully-contiguous chunks per tap (was 64B/skip/64B).
// Expect: FETCH 477MB -> ~310-390MB (128B line reuse) and/or better DRAM
// row locality. acc[2][4] = 32 VGPR, cap 128 @ 4 blocks/CU (LDS-limited,
// occupancy previously shown neutral). Grid: 2048 blocks.
// ---------------------------------------------------------------------------
__global__ __launch_bounds__(256, 4) void mapped_conv_mfma(
    const _Float16* __restrict__ xt,
    const float* __restrict__ weight,   // [COUT][CIN][KK] fp32
    const float* __restrict__ bias,     // [COUT]
    const float* __restrict__ sm,       // [HW_OUT][KK][2] fp32
    float* __restrict__ out) {          // [BB][COUT][HW_OUT] fp32
  __shared__ __align__(16) _Float16 w_lds[KK * COUT * CIN];  // 36 KB

  int t = threadIdx.x;
  // Stage weights: w_lds[(k*64 + o)*32 + c] = W[o][c][k] as f16.
  for (int j = t; j < COUT * CIN * KK; j += 256) {
    unsigned ju = (unsigned)j;
    unsigned o  = ju / 288u;
    unsigned rr = ju % 288u;
    unsigned c  = rr / 9u;
    unsigned k  = rr % 9u;
    w_lds[(k * 64u + o) * 32u + c] = (_Float16)weight[ju];
  }
  __syncthreads();

  int wave = t >> 6;
  int lane = t & 63;
  int m    = lane & 15;   // A-row: pixel; B-col: cout within N-tile
  int quad = lane >> 4;   // channel quarter (A) / k-chunk (B) / row group (C)

  int hw_base = blockIdx.x * 64 + wave * 16;      // 2048 blocks x 4 waves
  int hw = hw_base + m;

  const uint4* xt4 = (const uint4*)xt;

  f32x4 acc0[4] = {{0.f,0.f,0.f,0.f},{0.f,0.f,0.f,0.f},
                   {0.f,0.f,0.f,0.f},{0.f,0.f,0.f,0.f}};
  f32x4 acc1[4] = {{0.f,0.f,0.f,0.f},{0.f,0.f,0.f,0.f},
                   {0.f,0.f,0.f,0.f},{0.f,0.f,0.f,0.f}};

  const float* smp = sm + (size_t)hw * (KK * 2);
  const uint4* wbl = (const uint4*)w_lds + (size_t)(m * 4 + quad);

#pragma unroll 2
  for (int k = 0; k < KK; ++k) {
    float sx = smp[k * 2 + 0];
    float sy = smp[k * 2 + 1];
    float bxf = floorf(sx), byf = floorf(sy);
    float fx = sx - bxf, fy = sy - byf;
    int ix0 = (int)bxf, iy0 = (int)byf;
    int ix1 = min(ix0 + 1, W_IN - 1);
    int iy1 = min(iy0 + 1, H_IN - 1);
    ix0 = max(min(ix0, W_IN - 1), 0); ix1 = max(ix1, 0);
    iy0 = max(min(iy0, H_IN - 1), 0); iy1 = max(iy1, 0);

    int r00 = (iy0 * W_IN + ix0) * 8;
    int r01 = (iy0 * W_IN + ix1) * 8;
    int r10 = (iy1 * W_IN + ix0) * 8;
    int r11 = (iy1 * W_IN + ix1) * 8;

    // b0 half (granule quad) and b1 half (granule 4+quad) back-to-back:
    // same 128B record, issued temporally adjacent from the same wave.
    uint4 v00a = xt4[r00 + quad],     v00b = xt4[r00 + 4 + quad];
    uint4 v01a = xt4[r01 + quad],     v01b = xt4[r01 + 4 + quad];
    uint4 v10a = xt4[r10 + quad],     v10b = xt4[r10 + 4 + quad];
    uint4 v11a = xt4[r11 + quad],     v11b = xt4[r11 + 4 + quad];

    _Float16 w00 = (_Float16)((1.f - fx) * (1.f - fy));
    _Float16 w01 = (_Float16)(fx * (1.f - fy));
    _Float16 w10 = (_Float16)((1.f - fx) * fy);
    _Float16 w11 = (_Float16)(fx * fy);
    hf8 h00 = {w00, w00, w00, w00, w00, w00, w00, w00};
    hf8 h01 = {w01, w01, w01, w01, w01, w01, w01, w01};
    hf8 h10 = {w10, w10, w10, w10, w10, w10, w10, w10};
    hf8 h11 = {w11, w11, w11, w11, w11, w11, w11, w11};

    hf8 a0 = h00 * u4h(v00a) + h01 * u4h(v01a) + h10 * u4h(v10a) + h11 * u4h(v11a);
    hf8 a1 = h00 * u4h(v00b) + h01 * u4h(v01b) + h10 * u4h(v10b) + h11 * u4h(v11b);

    const uint4* wk = wbl + (size_t)k * 256;   // per-k block = 64 o * 4 granules
    hf8 b0 = u4h(wk[0]);
    hf8 b1 = u4h(wk[64]);
    hf8 b2 = u4h(wk[128]);
    hf8 b3 = u4h(wk[192]);

    acc0[0] = __builtin_amdgcn_mfma_f32_16x16x32_f16(a0, b0, acc0[0], 0, 0, 0);
    acc1[0] = __builtin_amdgcn_mfma_f32_16x16x32_f16(a1, b0, acc1[0], 0, 0, 0);
    acc0[1] = __builtin_amdgcn_mfma_f32_16x16x32_f16(a0, b1, acc0[1], 0, 0, 0);
    acc1[1] = __builtin_amdgcn_mfma_f32_16x16x32_f16(a1, b1, acc1[1], 0, 0, 0);
    acc0[2] = __builtin_amdgcn_mfma_f32_16x16x32_f16(a0, b2, acc0[2], 0, 0, 0);
    acc1[2] = __builtin_amdgcn_mfma_f32_16x16x32_f16(a1, b2, acc1[2], 0, 0, 0);
    acc0[3] = __builtin_amdgcn_mfma_f32_16x16x32_f16(a0, b3, acc0[3], 0, 0, 0);
    acc1[3] = __builtin_amdgcn_mfma_f32_16x16x32_f16(a1, b3, acc1[3], 0, 0, 0);
  }

  // Epilogue: lane writes 4 consecutive pixels (rows quad*4..+3) for cout n,
  // for both batches.
  int hw0 = hw_base + quad * 4;
#pragma unroll
  for (int nt = 0; nt < 4; ++nt) {
    int n = nt * 16 + m;
    float bn = bias[n];
    float4 v0 = make_float4(acc0[nt][0] + bn, acc0[nt][1] + bn,
                            acc0[nt][2] + bn, acc0[nt][3] + bn);
    float4 v1 = make_float4(acc1[nt][0] + bn, acc1[nt][1] + bn,
                            acc1[nt][2] + bn, acc1[nt][3] + bn);
    *(float4*)(out + (size_t)n * HW_OUT + hw0) = v0;
    *(float4*)(out + (size_t)(COUT + n) * HW_OUT + hw0) = v1;
  }
}

extern "C" void kernel_launch(void* const* d_in, const int* in_sizes, int n_in,
                              void* d_out, int out_size, void* d_ws, size_t ws_size,
                              hipStream_t stream) {
  const float* x  = (const float*)d_in[0];   // [B][CIN][H*W]
  const float* w  = (const float*)d_in[1];   // [COUT][CIN][KK]
  const float* bs = (const float*)d_in[2];   // [COUT]
  const float* sm = (const float*)d_in[3];   // [OH*OW][KK][2]
  float* out = (float*)d_out;                // [B][COUT][OH*OW]
  _Float16* xt = (_Float16*)d_ws;            // 16 MB scratch: (H*W, B, CIN) f16

  transpose_lds<<<dim3(512), dim3(256), 0, stream>>>(x, xt);
  mapped_conv_mfma<<<dim3(2048), dim3(256), 0, stream>>>(xt, w, bs, sm, out);
}